// Round 1
// baseline (94.412 us; speedup 1.0000x reference)
//
#include <hip/hip_runtime.h>
#include <math.h>

// RESUS_NN_2327872274812: Q=8192, S=30, D=512.  FP32-exact, deterministic.
// r15 = r14 + ONE change: 2 queries per thread (QT 16 -> 32, 256 blocks).
// Theory: r14's timed slice is LDS-return-pipe bound (~8.5us bill vs 4.8us
// VALU floor) because every support byte is ds_read once PER QUERY. Owning
// 2 queries per thread halves hot-loop LDS traffic per element (same 8
// ds_read_b128 per row now feed 384 VALU cyc, not 192) -> LDS bill ~4.3us,
// kernel becomes VALU-bound. VGPR ~180 -> 2 waves/SIMD (grid 2048 waves),
// i.e. r13's occupancy but with 2x per-wave ILP to cover ds_read latency.
// Reduction order unchanged everywhere -> absmax 0.0 preserved.
// thread = (ql 0..15, dseg 0..15, shalf 0..1): queries {ql, ql+16},
// 32-float d-slice, 5 support rows per pass.

#define QN 8192
#define SN 30
#define DN 512
#define BLK 512
#define QT 32            // queries per block (2 per thread)
#define SCHUNK 10        // support rows per pass
#define NPASS 3
#define SROW 580         // floats per LDS support row (16 segs * 36 + 4)
#define PRW 17           // praw q-slot stride (floats)
#define PSTR 31          // final part row stride (float2)

__global__ __launch_bounds__(BLK, 2)
void resus_one(const float* __restrict__ query,      // [Q][D]
               const float* __restrict__ support,    // [S][D]
               const float* __restrict__ support_y,  // [S]
               const float* __restrict__ support_pr, // [S]
               const float* __restrict__ query_pr,   // [Q]
               const float* __restrict__ fc1_w,      // [D]
               const float* __restrict__ adj_scale,  // [30]
               const float* __restrict__ adj_bias,   // [30]
               const int*   __restrict__ num_samples,// [1]
               float* __restrict__ out)              // [2*Q]
{
    __shared__ float  sp[SCHUNK * SROW];          // 23,200 B
    __shared__ float  praw_sc[SCHUNK * QT * PRW]; // 21,760 B
    __shared__ float  praw_sq[SCHUNK * QT * PRW]; // 21,760 B
    __shared__ float2 part[QT * PSTR];            //  7,936 B  total 74,656 B

    const int tid   = threadIdx.x;
    const int ql    = tid & 15;               // query slot (lane-fast)
    const int dseg  = (tid >> 4) & 15;        // 32-float d-segment
    const int shalf = tid >> 8;               // 0/1: which 5 rows of a chunk
    const int qA    = blockIdx.x * QT + ql;   // first query
    const int qB    = qA + 16;                // second query

    // ---- one-time: 2 q-slices + w slice into named regs, then PIN ----
    const float* qpA = query + (size_t)qA * DN + dseg * 32;
    float4 a0 = *reinterpret_cast<const float4*>(qpA +  0);
    float4 a1 = *reinterpret_cast<const float4*>(qpA +  4);
    float4 a2 = *reinterpret_cast<const float4*>(qpA +  8);
    float4 a3 = *reinterpret_cast<const float4*>(qpA + 12);
    float4 a4 = *reinterpret_cast<const float4*>(qpA + 16);
    float4 a5 = *reinterpret_cast<const float4*>(qpA + 20);
    float4 a6 = *reinterpret_cast<const float4*>(qpA + 24);
    float4 a7 = *reinterpret_cast<const float4*>(qpA + 28);
    const float* qpB = query + (size_t)qB * DN + dseg * 32;
    float4 b0 = *reinterpret_cast<const float4*>(qpB +  0);
    float4 b1 = *reinterpret_cast<const float4*>(qpB +  4);
    float4 b2 = *reinterpret_cast<const float4*>(qpB +  8);
    float4 b3 = *reinterpret_cast<const float4*>(qpB + 12);
    float4 b4 = *reinterpret_cast<const float4*>(qpB + 16);
    float4 b5 = *reinterpret_cast<const float4*>(qpB + 20);
    float4 b6 = *reinterpret_cast<const float4*>(qpB + 24);
    float4 b7 = *reinterpret_cast<const float4*>(qpB + 28);
    const float* wp = fc1_w + dseg * 32;
    float4 w0 = *reinterpret_cast<const float4*>(wp +  0);
    float4 w1 = *reinterpret_cast<const float4*>(wp +  4);
    float4 w2 = *reinterpret_cast<const float4*>(wp +  8);
    float4 w3 = *reinterpret_cast<const float4*>(wp + 12);
    float4 w4 = *reinterpret_cast<const float4*>(wp + 16);
    float4 w5 = *reinterpret_cast<const float4*>(wp + 20);
    float4 w6 = *reinterpret_cast<const float4*>(wp + 24);
    float4 w7 = *reinterpret_cast<const float4*>(wp + 28);

#define PIN4(V) asm volatile("" : "+v"((V).x), "+v"((V).y), "+v"((V).z), "+v"((V).w))
    PIN4(a0); PIN4(a1); PIN4(a2); PIN4(a3);
    PIN4(a4); PIN4(a5); PIN4(a6); PIN4(a7);
    PIN4(b0); PIN4(b1); PIN4(b2); PIN4(b3);
    PIN4(b4); PIN4(b5); PIN4(b6); PIN4(b7);
    PIN4(w0); PIN4(w1); PIN4(w2); PIN4(w3);
    PIN4(w4); PIN4(w5); PIN4(w6); PIN4(w7);
#undef PIN4

    // Per component: chain order for each query identical to r14 (sub,
    // fma(w,|d|,sc), fma(d,d,sq) in d-ascending order).  A and B chains
    // are independent -> 2x ILP per s-load.
#define ACC2(QA, QB, WV, SV) { float dA_, dB_; \
    dA_ = (QA).x - (SV).x; dB_ = (QB).x - (SV).x; \
    scA = fmaf((WV).x, fabsf(dA_), scA); sqA = fmaf(dA_, dA_, sqA); \
    scB = fmaf((WV).x, fabsf(dB_), scB); sqB = fmaf(dB_, dB_, sqB); \
    dA_ = (QA).y - (SV).y; dB_ = (QB).y - (SV).y; \
    scA = fmaf((WV).y, fabsf(dA_), scA); sqA = fmaf(dA_, dA_, sqA); \
    scB = fmaf((WV).y, fabsf(dB_), scB); sqB = fmaf(dB_, dB_, sqB); \
    dA_ = (QA).z - (SV).z; dB_ = (QB).z - (SV).z; \
    scA = fmaf((WV).z, fabsf(dA_), scA); sqA = fmaf(dA_, dA_, sqA); \
    scB = fmaf((WV).z, fabsf(dB_), scB); sqB = fmaf(dB_, dB_, sqB); \
    dA_ = (QA).w - (SV).w; dB_ = (QB).w - (SV).w; \
    scA = fmaf((WV).w, fabsf(dA_), scA); sqA = fmaf(dA_, dA_, sqA); \
    scB = fmaf((WV).w, fabsf(dB_), scB); sqB = fmaf(dB_, dB_, sqB); }

    const int sbase  = dseg * 36;
    const int pbaseA = ql * PRW + dseg;          // query slot ql
    const int pbaseB = (ql + 16) * PRW + dseg;   // query slot ql+16
    const int sl0    = shalf * (SCHUNK / 2);     // 0 or 5

    for (int pass = 0; pass < NPASS; ++pass) {
        __syncthreads();   // prev pass: sp reads + reduce complete

        // ---- stage 10 support rows (coalesced read -> segmented LDS) ----
        const float4* sg = reinterpret_cast<const float4*>(
            support + (size_t)pass * SCHUNK * DN);
        for (int i = tid; i < SCHUNK * 128; i += BLK) {
            const int row = i >> 7, c4 = i & 127;
            *reinterpret_cast<float4*>(
                sp + row * SROW + 36 * (c4 >> 3) + 4 * (c4 & 7)) = sg[i];
        }
        __syncthreads();

        // ---- hot loop: 5 rows per thread x 2 queries, no shuffles ----
#pragma unroll
        for (int k = 0; k < SCHUNK / 2; ++k) {
            const int sl = sl0 + k;
            const float* sr = sp + sl * SROW + sbase;
            const float4 s0 = *reinterpret_cast<const float4*>(sr +  0);
            const float4 s1 = *reinterpret_cast<const float4*>(sr +  4);
            const float4 s2 = *reinterpret_cast<const float4*>(sr +  8);
            const float4 s3 = *reinterpret_cast<const float4*>(sr + 12);
            const float4 s4 = *reinterpret_cast<const float4*>(sr + 16);
            const float4 s5 = *reinterpret_cast<const float4*>(sr + 20);
            const float4 s6 = *reinterpret_cast<const float4*>(sr + 24);
            const float4 s7 = *reinterpret_cast<const float4*>(sr + 28);

            float scA = 0.0f, sqA = 0.0f, scB = 0.0f, sqB = 0.0f;
            ACC2(a0, b0, w0, s0) ACC2(a1, b1, w1, s1)
            ACC2(a2, b2, w2, s2) ACC2(a3, b3, w3, s3)
            ACC2(a4, b4, w4, s4) ACC2(a5, b5, w5, s5)
            ACC2(a6, b6, w6, s6) ACC2(a7, b7, w7, s7)

            praw_sc[sl * (QT * PRW) + pbaseA] = scA;
            praw_sq[sl * (QT * PRW) + pbaseA] = sqA;
            praw_sc[sl * (QT * PRW) + pbaseB] = scB;
            praw_sq[sl * (QT * PRW) + pbaseB] = sqB;
        }
        __syncthreads();

        // ---- per-pass reduce over dseg: fixed ascending order ----
        if (tid < SCHUNK * QT) {           // 320 threads
            const int sl = tid >> 5, qq = tid & 31;
            const int b = sl * (QT * PRW) + qq * PRW;
            float sc = 0.0f, sq = 0.0f;
#pragma unroll
            for (int d = 0; d < 16; ++d) {
                sc += praw_sc[b + d];
                sq += praw_sq[b + d];
            }
            part[qq * PSTR + pass * SCHUNK + sl] = make_float2(sc, sq);
        }
    }
#undef ACC2
    __syncthreads();   // all part[] writes visible

    // ---- epilogue: 32 groups of 16 lanes; group g = query g ----
    // Lane handles s-pair (sA, sA+16); the explicit pre-add below is
    // bit-identical to r14's off=16 tree step, then same 8/4/2/1 tree.
    const int grp = tid >> 4;                 // 0..31
    const int sA  = tid & 15;                 // always < SN
    const int sB  = sA + 16;
    const bool vB = (sB < SN);

    const float dyA = support_y[sA] - 1.0f / (1.0f + expf(-support_pr[sA]));
    float dyB = 0.0f;
    if (vB)
        dyB = support_y[sB] - 1.0f / (1.0f + expf(-support_pr[sB]));

    const int ns = num_samples[0];
    const float ascale = fabsf(adj_scale[ns - 1]);
    const float abias  = adj_bias[ns - 1];

    const int qg = blockIdx.x * QT + grp;
    const float2 prA = part[grp * PSTR + sA];
    const float2 prB = part[grp * PSTR + (vB ? sB : 0)];

    const float scvA = prA.x;
    const float ssvA = prA.y;
    const float scvB = vB ? prB.x : -1e30f;
    const float ssvB = vB ? prB.y : 0.0f;

    float m = fmaxf(scvA, scvB);
#pragma unroll
    for (int off = 8; off >= 1; off >>= 1)
        m = fmaxf(m, __shfl_xor(m, off));

    const float eA = expf(scvA - m);
    const float eB = vB ? expf(scvB - m) : 0.0f;
    float den = eA + eB;
    // __fmul_rn/__fadd_rn: forbid fma contraction so rounding matches
    // r14's per-lane mul followed by the off=16 tree add.
    float num = __fadd_rn(__fmul_rn(dyA, eA), __fmul_rn(dyB, eB));
    float l2  = sqrtf(ssvA) + (vB ? sqrtf(ssvB) : 0.0f);
#pragma unroll
    for (int off = 8; off >= 1; off >>= 1) {
        den += __shfl_xor(den, off);
        num += __shfl_xor(num, off);
        l2  += __shfl_xor(l2,  off);
    }

    if (sA == 0) {
        out[qg]      = num / den * ascale + abias + query_pr[qg];
        out[QN + qg] = l2 * (1.0f / (float)SN);
    }
}

extern "C" void kernel_launch(void* const* d_in, const int* in_sizes, int n_in,
                              void* d_out, int out_size, void* d_ws, size_t ws_size,
                              hipStream_t stream)
{
    const float* query      = (const float*)d_in[0];
    const float* support    = (const float*)d_in[1];
    const float* support_y  = (const float*)d_in[2];
    const float* support_pr = (const float*)d_in[3];
    const float* query_pr   = (const float*)d_in[4];
    const float* fc1_w      = (const float*)d_in[5];
    // d_in[6] = fc1_b: cancels in softmax, unused
    const float* adj_scale  = (const float*)d_in[7];
    const float* adj_bias   = (const float*)d_in[8];
    const int*   num_s      = (const int*)d_in[9];
    float* out = (float*)d_out;

    dim3 grid(QN / QT);      // 256 blocks x 8 waves = 1 block/CU, 2 waves/SIMD
    hipLaunchKernelGGL(resus_one, grid, dim3(BLK), 0, stream,
                       query, support, support_y, support_pr, query_pr,
                       fc1_w, adj_scale, adj_bias, num_s, out);
}

// Round 2
// 94.002 us; speedup vs baseline: 1.0044x; 1.0044x over previous
//
#include <hip/hip_runtime.h>
#include <math.h>

// RESUS_NN_2327872274812: Q=8192, S=30, D=512.  FP32-exact, deterministic.
// r16 = r14 geometry (QT=16, 512 blocks, 2 blocks/CU, 4 waves/SIMD; r15's
// 2-q/thread regressed -1us -> reverted) + ONE structural change: hide the
// query-load HBM burst under pass-0 compute.
//   r14's PIN4 right after the q/w loads forced s_waitcnt vmcnt(0) -> the
//   16.8 MB query read (2.7us chip-wide at 6.3 TB/s) was fully serial
//   before any compute. Model: 2.7 + 4.8 (VALU floor) + 1.2 (overheads)
//   = 8.7us ~ observed 8.9us kernel slice.
// Fix: (1) issue pass-0 support staging loads FIRST (their ds_write then
// waits at vmcnt(24), excluding q/w loads -- vmcnt is issue-ordered);
// (2) q/w loads issued per-segment-interleaved; (3) pass 0 runs d-seg-outer
// / row-inner so segment j only needs a_j/w_j -> compiler emits fine
// vmcnt(N) waits and compute overlaps remaining HBM delivery; (4) PIN4
// moved to after pass 0. Per-(q,row) accumulation stays d-ascending and
// reduce/epilogue orders are r14-identical -> absmax 0.0 preserved.
// thread = (ql 0..15, dseg 0..15, shalf 0..1): query ql, 32-float d-slice,
// 5 support rows per pass (shalf picks which half of the 10-row chunk).

#define QN 8192
#define SN 30
#define DN 512
#define BLK 512
#define QT 16            // queries per block
#define SCHUNK 10        // support rows per pass
#define NPASS 3
#define SROW 580         // floats per LDS support row (16 segs * 36 + 4)
#define PRW 17           // praw ql-dim stride (floats)
#define PSTR 31          // final part row stride (float2)

__global__ __launch_bounds__(BLK, 2)
void resus_one(const float* __restrict__ query,      // [Q][D]
               const float* __restrict__ support,    // [S][D]
               const float* __restrict__ support_y,  // [S]
               const float* __restrict__ support_pr, // [S]
               const float* __restrict__ query_pr,   // [Q]
               const float* __restrict__ fc1_w,      // [D]
               const float* __restrict__ adj_scale,  // [30]
               const float* __restrict__ adj_bias,   // [30]
               const int*   __restrict__ num_samples,// [1]
               float* __restrict__ out)              // [2*Q]
{
    __shared__ float  sp[SCHUNK * SROW];          // 23,200 B
    __shared__ float  praw_sc[SCHUNK * QT * PRW]; // 10,880 B
    __shared__ float  praw_sq[SCHUNK * QT * PRW]; // 10,880 B
    __shared__ float2 part[QT * PSTR];            //  3,968 B  total 48,928 B

    const int tid   = threadIdx.x;
    const int ql    = tid & 15;               // query slot (lane-fast)
    const int dseg  = (tid >> 4) & 15;        // 32-float d-segment
    const int shalf = tid >> 8;               // 0/1: which 5 rows of a chunk
    const int q     = blockIdx.x * QT + ql;

    // ---- pass-0 staging loads FIRST: their ds_write wait excludes q/w ----
    const float4* sg0 = reinterpret_cast<const float4*>(support);
    float4 g0 = sg0[tid];                     // SCHUNK*128 = 1280 float4s
    float4 g1 = sg0[tid + 512];
    float4 g2;
    const bool has2 = (tid < 256);            // 1280 - 1024
    if (has2) g2 = sg0[tid + 1024];

    // ---- q + w slices, per-segment interleaved issue order ----
    const float* qp = query + (size_t)q * DN + dseg * 32;
    const float* wp = fc1_w + dseg * 32;
    float4 a0 = *reinterpret_cast<const float4*>(qp +  0);
    float4 w0 = *reinterpret_cast<const float4*>(wp +  0);
    float4 a1 = *reinterpret_cast<const float4*>(qp +  4);
    float4 w1 = *reinterpret_cast<const float4*>(wp +  4);
    float4 a2 = *reinterpret_cast<const float4*>(qp +  8);
    float4 w2 = *reinterpret_cast<const float4*>(wp +  8);
    float4 a3 = *reinterpret_cast<const float4*>(qp + 12);
    float4 w3 = *reinterpret_cast<const float4*>(wp + 12);
    float4 a4 = *reinterpret_cast<const float4*>(qp + 16);
    float4 w4 = *reinterpret_cast<const float4*>(wp + 16);
    float4 a5 = *reinterpret_cast<const float4*>(qp + 20);
    float4 w5 = *reinterpret_cast<const float4*>(wp + 20);
    float4 a6 = *reinterpret_cast<const float4*>(qp + 24);
    float4 w6 = *reinterpret_cast<const float4*>(wp + 24);
    float4 a7 = *reinterpret_cast<const float4*>(qp + 28);
    float4 w7 = *reinterpret_cast<const float4*>(wp + 28);

    // ---- scatter staged rows into segmented LDS layout ----
    {
        int i = tid, row = i >> 7, c4 = i & 127;
        *reinterpret_cast<float4*>(sp + row * SROW + 36 * (c4 >> 3) + 4 * (c4 & 7)) = g0;
        i = tid + 512; row = i >> 7; c4 = i & 127;
        *reinterpret_cast<float4*>(sp + row * SROW + 36 * (c4 >> 3) + 4 * (c4 & 7)) = g1;
        if (has2) {
            i = tid + 1024; row = i >> 7; c4 = i & 127;
            *reinterpret_cast<float4*>(sp + row * SROW + 36 * (c4 >> 3) + 4 * (c4 & 7)) = g2;
        }
    }
    __syncthreads();

    // per-component chain: sub, fma(w,|d|,sc), fma(d,d,sq), d-ascending --
    // identical rounding to r14 for every (q, row).
#define ACCD(QV, WV, SV, SC, SQ) { float d_; \
    d_ = (QV).x - (SV).x; SC = fmaf((WV).x, fabsf(d_), SC); SQ = fmaf(d_, d_, SQ); \
    d_ = (QV).y - (SV).y; SC = fmaf((WV).y, fabsf(d_), SC); SQ = fmaf(d_, d_, SQ); \
    d_ = (QV).z - (SV).z; SC = fmaf((WV).z, fabsf(d_), SC); SQ = fmaf(d_, d_, SQ); \
    d_ = (QV).w - (SV).w; SC = fmaf((WV).w, fabsf(d_), SC); SQ = fmaf(d_, d_, SQ); }

    const int sbase = dseg * 36;
    const int pbase = ql * PRW + dseg;        // praw offset (sl adds QT*PRW)
    const int sl0   = shalf * (SCHUNK / 2);   // 0 or 5

    // ---- pass 0: d-seg-outer / row-inner; seg j waits only on a_j/w_j ----
    {
        const float* r0 = sp + (sl0 + 0) * SROW + sbase;
        const float* r1 = sp + (sl0 + 1) * SROW + sbase;
        const float* r2 = sp + (sl0 + 2) * SROW + sbase;
        const float* r3 = sp + (sl0 + 3) * SROW + sbase;
        const float* r4 = sp + (sl0 + 4) * SROW + sbase;
        float sc0 = 0.0f, sc1 = 0.0f, sc2 = 0.0f, sc3 = 0.0f, sc4 = 0.0f;
        float sq0 = 0.0f, sq1 = 0.0f, sq2 = 0.0f, sq3 = 0.0f, sq4 = 0.0f;

#define SEG0(AJ, WJ, OFF) { float4 s_; \
    s_ = *reinterpret_cast<const float4*>(r0 + (OFF)); ACCD(AJ, WJ, s_, sc0, sq0); \
    s_ = *reinterpret_cast<const float4*>(r1 + (OFF)); ACCD(AJ, WJ, s_, sc1, sq1); \
    s_ = *reinterpret_cast<const float4*>(r2 + (OFF)); ACCD(AJ, WJ, s_, sc2, sq2); \
    s_ = *reinterpret_cast<const float4*>(r3 + (OFF)); ACCD(AJ, WJ, s_, sc3, sq3); \
    s_ = *reinterpret_cast<const float4*>(r4 + (OFF)); ACCD(AJ, WJ, s_, sc4, sq4); }

        SEG0(a0, w0,  0) SEG0(a1, w1,  4) SEG0(a2, w2,  8) SEG0(a3, w3, 12)
        SEG0(a4, w4, 16) SEG0(a5, w5, 20) SEG0(a6, w6, 24) SEG0(a7, w7, 28)
#undef SEG0

        praw_sc[(sl0 + 0) * (QT * PRW) + pbase] = sc0;
        praw_sq[(sl0 + 0) * (QT * PRW) + pbase] = sq0;
        praw_sc[(sl0 + 1) * (QT * PRW) + pbase] = sc1;
        praw_sq[(sl0 + 1) * (QT * PRW) + pbase] = sq1;
        praw_sc[(sl0 + 2) * (QT * PRW) + pbase] = sc2;
        praw_sq[(sl0 + 2) * (QT * PRW) + pbase] = sq2;
        praw_sc[(sl0 + 3) * (QT * PRW) + pbase] = sc3;
        praw_sq[(sl0 + 3) * (QT * PRW) + pbase] = sq3;
        praw_sc[(sl0 + 4) * (QT * PRW) + pbase] = sc4;
        praw_sq[(sl0 + 4) * (QT * PRW) + pbase] = sq4;
    }

    // ---- NOW pin q/w for passes 1-2 (r11-proven; placed here so it does
    //      not force a vmcnt(0) drain before pass 0) ----
#define PIN4(V) asm volatile("" : "+v"((V).x), "+v"((V).y), "+v"((V).z), "+v"((V).w))
    PIN4(a0); PIN4(a1); PIN4(a2); PIN4(a3);
    PIN4(a4); PIN4(a5); PIN4(a6); PIN4(a7);
    PIN4(w0); PIN4(w1); PIN4(w2); PIN4(w3);
    PIN4(w4); PIN4(w5); PIN4(w6); PIN4(w7);
#undef PIN4

    __syncthreads();

    // ---- pass-0 reduce over dseg: fixed ascending order ----
    if (tid < SCHUNK * QT) {           // 160 threads
        const int sl = tid >> 4, qq = tid & 15;
        const int b = sl * (QT * PRW) + qq * PRW;
        float sc = 0.0f, sq = 0.0f;
#pragma unroll
        for (int d = 0; d < 16; ++d) {
            sc += praw_sc[b + d];
            sq += praw_sq[b + d];
        }
        part[qq * PSTR + sl] = make_float2(sc, sq);
    }

    // hot-loop macro for passes 1-2 (ambient sc/sq), r14-identical
#define ACC4(QV, WV, SV) { float d_; \
    d_ = (QV).x - (SV).x; sc = fmaf((WV).x, fabsf(d_), sc); sq = fmaf(d_, d_, sq); \
    d_ = (QV).y - (SV).y; sc = fmaf((WV).y, fabsf(d_), sc); sq = fmaf(d_, d_, sq); \
    d_ = (QV).z - (SV).z; sc = fmaf((WV).z, fabsf(d_), sc); sq = fmaf(d_, d_, sq); \
    d_ = (QV).w - (SV).w; sc = fmaf((WV).w, fabsf(d_), sc); sq = fmaf(d_, d_, sq); }

    for (int pass = 1; pass < NPASS; ++pass) {
        __syncthreads();   // prev pass: sp reads + reduce complete

        // ---- stage 10 support rows (coalesced read -> segmented LDS) ----
        const float4* sg = reinterpret_cast<const float4*>(
            support + (size_t)pass * SCHUNK * DN);
        for (int i = tid; i < SCHUNK * 128; i += BLK) {
            const int row = i >> 7, c4 = i & 127;
            *reinterpret_cast<float4*>(
                sp + row * SROW + 36 * (c4 >> 3) + 4 * (c4 & 7)) = sg[i];
        }
        __syncthreads();

        // ---- hot loop: 5 rows per thread, no shuffles, no atomics ----
#pragma unroll
        for (int k = 0; k < SCHUNK / 2; ++k) {
            const int sl = sl0 + k;
            const float* sr = sp + sl * SROW + sbase;
            const float4 s0 = *reinterpret_cast<const float4*>(sr +  0);
            const float4 s1 = *reinterpret_cast<const float4*>(sr +  4);
            const float4 s2 = *reinterpret_cast<const float4*>(sr +  8);
            const float4 s3 = *reinterpret_cast<const float4*>(sr + 12);
            const float4 s4 = *reinterpret_cast<const float4*>(sr + 16);
            const float4 s5 = *reinterpret_cast<const float4*>(sr + 20);
            const float4 s6 = *reinterpret_cast<const float4*>(sr + 24);
            const float4 s7 = *reinterpret_cast<const float4*>(sr + 28);

            float sc = 0.0f, sq = 0.0f;
            ACC4(a0, w0, s0) ACC4(a1, w1, s1)
            ACC4(a2, w2, s2) ACC4(a3, w3, s3)
            ACC4(a4, w4, s4) ACC4(a5, w5, s5)
            ACC4(a6, w6, s6) ACC4(a7, w7, s7)

            praw_sc[sl * (QT * PRW) + pbase] = sc;
            praw_sq[sl * (QT * PRW) + pbase] = sq;
        }
        __syncthreads();

        // ---- per-pass reduce over dseg: fixed order, deterministic ----
        if (tid < SCHUNK * QT) {           // 160 threads
            const int sl = tid >> 4, qq = tid & 15;
            const int b = sl * (QT * PRW) + qq * PRW;
            float sc = 0.0f, sq = 0.0f;
#pragma unroll
            for (int d = 0; d < 16; ++d) {
                sc += praw_sc[b + d];
                sq += praw_sq[b + d];
            }
            part[qq * PSTR + pass * SCHUNK + sl] = make_float2(sc, sq);
        }
    }
#undef ACC4
#undef ACCD
    __syncthreads();   // all part[] writes visible

    // ---- epilogue: 16 half-wave groups; group g = query g (r14) ----
    const int grp  = tid >> 5;                // 0..15
    const int s32  = tid & 31;
    const bool valid = (s32 < SN);
    const int  si  = valid ? s32 : 0;

    float dy = 0.0f;
    if (valid)
        dy = support_y[s32] - 1.0f / (1.0f + expf(-support_pr[s32]));

    const int ns = num_samples[0];
    const float ascale = fabsf(adj_scale[ns - 1]);
    const float abias  = adj_bias[ns - 1];

    const int qg = blockIdx.x * QT + grp;
    const float2 pr = part[grp * PSTR + si];

    float scv = valid ? pr.x : -1e30f;
    float ssv = valid ? pr.y : 0.0f;

    float m = scv;
#pragma unroll
    for (int off = 16; off >= 1; off >>= 1)
        m = fmaxf(m, __shfl_xor(m, off));

    float e   = valid ? expf(scv - m) : 0.0f;
    float den = e;
    float num = dy * e;
    float l2  = valid ? sqrtf(ssv) : 0.0f;
#pragma unroll
    for (int off = 16; off >= 1; off >>= 1) {
        den += __shfl_xor(den, off);
        num += __shfl_xor(num, off);
        l2  += __shfl_xor(l2,  off);
    }

    if (s32 == 0) {
        out[qg]      = num / den * ascale + abias + query_pr[qg];
        out[QN + qg] = l2 * (1.0f / (float)SN);
    }
}

extern "C" void kernel_launch(void* const* d_in, const int* in_sizes, int n_in,
                              void* d_out, int out_size, void* d_ws, size_t ws_size,
                              hipStream_t stream)
{
    const float* query      = (const float*)d_in[0];
    const float* support    = (const float*)d_in[1];
    const float* support_y  = (const float*)d_in[2];
    const float* support_pr = (const float*)d_in[3];
    const float* query_pr   = (const float*)d_in[4];
    const float* fc1_w      = (const float*)d_in[5];
    // d_in[6] = fc1_b: cancels in softmax, unused
    const float* adj_scale  = (const float*)d_in[7];
    const float* adj_bias   = (const float*)d_in[8];
    const int*   num_s      = (const int*)d_in[9];
    float* out = (float*)d_out;

    dim3 grid(QN / QT);      // 512 blocks x 8 waves = 4096 waves = 4/SIMD
    hipLaunchKernelGGL(resus_one, grid, dim3(BLK), 0, stream,
                       query, support, support_y, support_pr, query_pr,
                       fc1_w, adj_scale, adj_bias, num_s, out);
}